// Round 6
// baseline (706.737 us; speedup 1.0000x reference)
//
#include <hip/hip_runtime.h>
#include <math.h>

// Problem constants
#define DIMD 512
#define QS 64
#define KS 256
#define WIN 4
#define BATCH 8
#define RANK 32
#define NQ 1024             // q tokens per batch
#define NK 4096             // kv tokens per batch
#define MQ (BATCH*NQ)       // 8192 q rows
#define MK (BATCH*NK)       // 32768 kv rows

typedef unsigned short u16;
typedef __attribute__((ext_vector_type(8))) short bf16x8;  // MFMA A/B frag (8 bf16)
typedef __attribute__((ext_vector_type(4))) float f32x4;   // MFMA C/D frag

__device__ inline u16 f2bf(float x) {
    union { float f; unsigned int u; } v; v.f = x;
    unsigned int r = v.u + 0x7FFF + ((v.u >> 16) & 1);
    return (u16)(r >> 16);
}
__device__ inline float bf2f(u16 x) {
    union { unsigned int u; float f; } v; v.u = ((unsigned int)x) << 16;
    return v.f;
}

// async global->LDS, 16 B per lane. LDS dest = wave-uniform base + lane*16.
__device__ __forceinline__ void gload16(const u16* g, u16* l) {
    __builtin_amdgcn_global_load_lds(
        (const __attribute__((address_space(1))) void*)g,
        (__attribute__((address_space(3))) void*)l, 16, 0, 0);
}

// ---------------------------------------------------------------------------
// Flag helpers. Producers: RELEASE fetch_add (flushes XCD L2 before signal).
// Consumers: RELAXED spin (no acquire-inv needed: consumer XCDs cannot hold
// stale lines for data they never read; kernel-entry acquire covers history).
// Spin bounded so a logic bug fails the bench instead of hanging the GPU.
// ---------------------------------------------------------------------------
__device__ __forceinline__ void sigflag(int* f) {
    __hip_atomic_fetch_add(f, 1, __ATOMIC_RELEASE, __HIP_MEMORY_SCOPE_AGENT);
}
__device__ __forceinline__ void waitflag(int* f, int target) {
    if (threadIdx.x == 0) {
        for (int i = 0; i < (1 << 22); i++) {
            if (__hip_atomic_load(f, __ATOMIC_RELAXED, __HIP_MEMORY_SCOPE_AGENT) >= target)
                break;
            __builtin_amdgcn_s_sleep(8);
        }
    }
    __syncthreads();
}

// ===========================================================================
// Phase bodies
// ===========================================================================

// FiLM: whole conditioning chain for one batch b in one block.
// h = silu(ctx0@Wc0 + bc0 + ctx1@Wc1 + bc1) ; gamma,beta = split(h@Wf + bf)
__device__ __forceinline__ void film_body(
    int b, const float* __restrict__ ctx0, const float* __restrict__ ctx1,
    const float* __restrict__ Wc0, const float* __restrict__ bc0,
    const float* __restrict__ Wc1, const float* __restrict__ bc1,
    const float* __restrict__ Wf, const float* __restrict__ bfv,
    float* __restrict__ gamma, float* __restrict__ beta, float* hL)
{
    int t = threadIdx.x;
    const float* c0 = ctx0 + b * DIMD;
    const float* c1 = ctx1 + b * DIMD;
    #pragma unroll
    for (int half = 0; half < 2; half++) {
        int d = t + half * 256;
        float acc = bc0[d] + bc1[d];
        #pragma unroll 4
        for (int i = 0; i < DIMD; i++)
            acc = fmaf(c0[i], Wc0[i * DIMD + d], fmaf(c1[i], Wc1[i * DIMD + d], acc));
        hL[d] = acc / (1.f + expf(-acc));
    }
    __syncthreads();
    #pragma unroll
    for (int half = 0; half < 2; half++) {
        int d = t + half * 256;
        float ga = 0.f, be = 0.f;
        #pragma unroll 4
        for (int i = 0; i < DIMD; i++) {
            float hv = hL[i];
            ga = fmaf(hv, Wf[i * 2 * DIMD + d], ga);
            be = fmaf(hv, Wf[i * 2 * DIMD + DIMD + d], be);
        }
        gamma[b * DIMD + d] = ga + bfv[d];
        beta[b * DIMD + d]  = be + bfv[DIMD + d];
    }
}

// gatefuse with Wg staged in LDS: dst[off+r][k] = sum_j W[k][j]*Wg[j][r]
__device__ __forceinline__ void gatefuse_body(
    int gid, const float* __restrict__ W, const float* __restrict__ Wg,
    u16* __restrict__ dst, int off, float* WgL)
{
    int t = threadIdx.x;
    for (int i = t; i < 4096; i += 256)
        ((float4*)WgL)[i] = ((const float4*)Wg)[i];
    __syncthreads();
    int idx = gid * 256 + t;            // 0..16383
    int r = idx & 31, k = idx >> 5;
    const float* Wr = W + (long)k * DIMD;
    float acc = 0.f;
    #pragma unroll 4
    for (int j = 0; j < DIMD; j += 4) {
        float4 w4 = *(const float4*)&Wr[j];
        acc = fmaf(w4.x, WgL[(j + 0) * 32 + r], acc);
        acc = fmaf(w4.y, WgL[(j + 1) * 32 + r], acc);
        acc = fmaf(w4.z, WgL[(j + 2) * 32 + r], acc);
        acc = fmaf(w4.w, WgL[(j + 3) * 32 + r], acc);
    }
    dst[(long)(off + r) * DIMD + k] = f2bf(acc);
}

// transpose W[512][512] fp32 -> bf16 dst[off + n][k]
__device__ __forceinline__ void transpose_body(
    int i, const float* __restrict__ src, u16* __restrict__ dst, int off,
    float (*tile)[33])
{
    int t = threadIdx.x;
    int tx = t & 31, ty = t >> 5;
    int bx = (i & 15) * 32;
    int by = (i >> 4) * 32;
    #pragma unroll
    for (int k = 0; k < 4; k++)
        tile[ty + k * 8][tx] = src[(long)(by + ty + k * 8) * DIMD + bx + tx];
    __syncthreads();
    #pragma unroll
    for (int k = 0; k < 4; k++)
        dst[(long)(off + bx + ty + k * 8) * DIMD + by + tx] = f2bf(tile[tx][ty + k * 8]);
}

__device__ __forceinline__ void biascat3_body(
    int bid, const float* __restrict__ b0, const float* __restrict__ b1,
    const float* __restrict__ Wg, float* __restrict__ dst)
{
    int t = bid * 256 + threadIdx.x;
    if (t < 512) dst[t] = b0[t];
    else if (t < 1024) dst[t] = b1[t - 512];
    else if (t < 1056) {
        int r = t - 1024;
        float a = 0.f;
        for (int j = 0; j < DIMD; j++) a = fmaf(b0[j], Wg[j * RANK + r], a);
        dst[t] = a;
    }
}
__device__ __forceinline__ void biascat2_body(
    int bid, const float* __restrict__ b0, const float* __restrict__ Wg,
    float* __restrict__ dst)
{
    int t = bid * 256 + threadIdx.x;
    if (t < 512) dst[t] = b0[t];
    else if (t < 544) {
        int r = t - 512;
        float a = 0.f;
        for (int j = 0; j < DIMD; j++) a = fmaf(b0[j], Wg[j * RANK + r], a);
        dst[t] = a;
    }
}

// norm (LN*g+b -> bf16): 16 rows/block, 4 rows per wave (ILP at low occupancy)
__device__ __forceinline__ void norm0_body(
    int bid, const float* __restrict__ X, const float* __restrict__ g,
    const float* __restrict__ bb, u16* __restrict__ out)
{
    int wave = threadIdx.x >> 6, lane = threadIdx.x & 63;
    int c = lane * 8;
    float4 g0 = *(const float4*)&g[c],  g1 = *(const float4*)&g[c + 4];
    float4 b0 = *(const float4*)&bb[c], b1 = *(const float4*)&bb[c + 4];
    long row0 = (long)bid * 16 + wave * 4;
    #pragma unroll
    for (int rr = 0; rr < 4; rr++) {
        long row = row0 + rr;
        const float* x = X + row * DIMD;
        float4 a = *(const float4*)&x[c];
        float4 b = *(const float4*)&x[c + 4];
        float s  = a.x + a.y + a.z + a.w + b.x + b.y + b.z + b.w;
        float ss = a.x*a.x + a.y*a.y + a.z*a.z + a.w*a.w
                 + b.x*b.x + b.y*b.y + b.z*b.z + b.w*b.w;
        #pragma unroll
        for (int o = 1; o < 64; o <<= 1) { s += __shfl_xor(s, o); ss += __shfl_xor(ss, o); }
        float mu = s * (1.f / DIMD);
        float var = ss * (1.f / DIMD) - mu * mu;
        float rs = rsqrtf(var + 1e-5f);
        u16 o8[8];
        o8[0] = f2bf((a.x - mu) * rs * g0.x + b0.x);
        o8[1] = f2bf((a.y - mu) * rs * g0.y + b0.y);
        o8[2] = f2bf((a.z - mu) * rs * g0.z + b0.z);
        o8[3] = f2bf((a.w - mu) * rs * g0.w + b0.w);
        o8[4] = f2bf((b.x - mu) * rs * g1.x + b1.x);
        o8[5] = f2bf((b.y - mu) * rs * g1.y + b1.y);
        o8[6] = f2bf((b.z - mu) * rs * g1.z + b1.z);
        o8[7] = f2bf((b.w - mu) * rs * g1.w + b1.w);
        *(int4*)&out[row * DIMD + c] = *(const int4*)o8;
    }
}

// row stats: 16 rows/block, 4 per wave
__device__ __forceinline__ void stats_body(
    int bid, const float* __restrict__ X, float* __restrict__ mu_o, float* __restrict__ rs_o)
{
    int wave = threadIdx.x >> 6, lane = threadIdx.x & 63;
    int c = lane * 8;
    long row0 = (long)bid * 16 + wave * 4;
    #pragma unroll
    for (int rr = 0; rr < 4; rr++) {
        long row = row0 + rr;
        const float* x = X + row * DIMD;
        float4 a = *(const float4*)&x[c];
        float4 b = *(const float4*)&x[c + 4];
        float s  = a.x + a.y + a.z + a.w + b.x + b.y + b.z + b.w;
        float ss = a.x*a.x + a.y*a.y + a.z*a.z + a.w*a.w
                 + b.x*b.x + b.y*b.y + b.z*b.z + b.w*b.w;
        #pragma unroll
        for (int o = 1; o < 64; o <<= 1) { s += __shfl_xor(s, o); ss += __shfl_xor(ss, o); }
        if (lane == 0) {
            float mu = s * (1.f / DIMD);
            float var = ss * (1.f / DIMD) - mu * mu;
            mu_o[row] = mu;
            rs_o[row] = rsqrtf(var + 1e-5f);
        }
    }
}

// ---------------------------------------------------------------------------
// bf16 MFMA GEMM body (m97 structure)
// ---------------------------------------------------------------------------
template<int NSEC, bool BF>
__device__ __forceinline__ void gemm_body(
    int m0, int n0, const u16* __restrict__ A, const u16* __restrict__ Bt,
    const float* __restrict__ biascat,
    void* __restrict__ C0v, void* __restrict__ C1v, void* __restrict__ Cgv,
    int Nvalid, u16* smem)
{
    u16* As = smem;
    u16* Bs = smem + 4096;
    int t = threadIdx.x;
    int wave = t >> 6, lane = t & 63;
    int mhalf = (wave >> 1) * 64, nhalf = (wave & 1) * 64;
    int lm = lane & 15, quad = lane >> 4;

    int srow = wave * 32 + (lane >> 2);
    int scol = (lane & 3) * 8;
    const u16* Ag = A + (long)(m0 + srow) * DIMD + scol;
    const u16* Bg = Bt + (long)(n0 + srow) * DIMD + scol;
    u16* Asl = As + wave * 1024 + lane * 8;
    u16* Bsl = Bs + wave * 1024 + lane * 8;

    f32x4 acc[4][4];
    #pragma unroll
    for (int i = 0; i < 4; i++)
        #pragma unroll
        for (int j = 0; j < 4; j++)
            acc[i][j] = (f32x4){0.f, 0.f, 0.f, 0.f};

    for (int k0 = 0; k0 < DIMD; k0 += 32) {
        __syncthreads();
        gload16(Ag + k0, Asl);
        gload16(Ag + 16 * DIMD + k0, Asl + 512);
        gload16(Bg + k0, Bsl);
        gload16(Bg + 16 * DIMD + k0, Bsl + 512);
        __syncthreads();
        bf16x8 af[4], bfr[4];
        #pragma unroll
        for (int i = 0; i < 4; i++) {
            af[i]  = *(const bf16x8*)&As[(mhalf + i * 16 + lm) * 32 + quad * 8];
            bfr[i] = *(const bf16x8*)&Bs[(nhalf + i * 16 + lm) * 32 + quad * 8];
        }
        #pragma unroll
        for (int i = 0; i < 4; i++)
            #pragma unroll
            for (int j = 0; j < 4; j++)
                acc[i][j] = __builtin_amdgcn_mfma_f32_16x16x32_bf16(af[i], bfr[j], acc[i][j], 0, 0, 0);
    }

    float biasj[4];
    #pragma unroll
    for (int j = 0; j < 4; j++) biasj[j] = biascat[n0 + nhalf + j * 16 + lm];

    if (BF) {
        for (int i = 0; i < 4; i++) {
            __syncthreads();
            #pragma unroll
            for (int j = 0; j < 4; j++)
                #pragma unroll
                for (int r = 0; r < 4; r++)
                    smem[((wave >> 1) * 16 + quad * 4 + r) * 128 + nhalf + j * 16 + lm] =
                        f2bf(acc[i][j][r] + biasj[j]);
            __syncthreads();
            #pragma unroll
            for (int u = 0; u < 2; u++) {
                int cch = t + u * 256;
                int R = cch >> 4, ci = cch & 15;
                long grow = m0 + (R >> 4) * 64 + i * 16 + (R & 15);
                int gcol = n0 + ci * 8;
                int4 val = *(const int4*)&smem[R * 128 + ci * 8];
                if (NSEC == 1) {
                    *(int4*)((u16*)C0v + grow * 512 + gcol) = val;
                } else if (NSEC == 2) {
                    if (gcol < 512)          *(int4*)((u16*)C0v + grow * 512 + gcol) = val;
                    else if (gcol < Nvalid)  *(int4*)((u16*)Cgv + grow * 32 + (gcol - 512)) = val;
                } else {
                    if (gcol < 512)          *(int4*)((u16*)C0v + grow * 512 + gcol) = val;
                    else if (gcol < 1024)    *(int4*)((u16*)C1v + grow * 512 + (gcol - 512)) = val;
                    else if (gcol < Nvalid)  *(int4*)((u16*)Cgv + grow * 32 + (gcol - 1024)) = val;
                }
            }
        }
    } else {
        float* Stg = (float*)smem;
        for (int i = 0; i < 4; i++) {
            __syncthreads();
            #pragma unroll
            for (int j = 0; j < 4; j++)
                #pragma unroll
                for (int r = 0; r < 4; r++)
                    Stg[((wave >> 1) * 16 + quad * 4 + r) * 128 + nhalf + j * 16 + lm] =
                        acc[i][j][r] + biasj[j];
            __syncthreads();
            #pragma unroll
            for (int u = 0; u < 4; u++) {
                int cch = t + u * 256;
                int R = cch >> 5, ci = cch & 31;
                long grow = m0 + (R >> 4) * 64 + i * 16 + (R & 15);
                int gcol = n0 + ci * 4;
                *(float4*)((float*)C0v + grow * 512 + gcol) = *(const float4*)&Stg[R * 128 + ci * 4];
            }
        }
    }
}

// ---------------------------------------------------------------------------
// q projection GEMM body: LN+FiLM fused into A-staging
// ---------------------------------------------------------------------------
__device__ __forceinline__ void qproj_body(
    int m0, int n0, const float* __restrict__ query, const float* __restrict__ mu_q,
    const float* __restrict__ rs_q, const float* __restrict__ qn_g,
    const float* __restrict__ qn_b, const float* __restrict__ gamma,
    const float* __restrict__ beta, const u16* __restrict__ Btq,
    const float* __restrict__ biasq, u16* __restrict__ qp, u16* __restrict__ gq,
    u16* smem)
{
    u16* As = smem;
    u16* Bs = smem + 4096;
    int t = threadIdx.x;
    int wave = t >> 6, lane = t & 63;
    int mhalf = (wave >> 1) * 64, nhalf = (wave & 1) * 64;
    int lm = lane & 15, quad = lane >> 4;
    int bt = m0 >> 10;

    int srow = wave * 32 + (lane >> 2);
    int scol = (lane & 3) * 8;
    const u16* Bg = Btq + (long)(n0 + srow) * DIMD + scol;
    u16* Bsl = Bs + wave * 1024 + lane * 8;

    f32x4 acc[4][4];
    #pragma unroll
    for (int i = 0; i < 4; i++)
        #pragma unroll
        for (int j = 0; j < 4; j++)
            acc[i][j] = (f32x4){0.f, 0.f, 0.f, 0.f};

    for (int k0 = 0; k0 < DIMD; k0 += 32) {
        __syncthreads();
        gload16(Bg + k0, Bsl);
        gload16(Bg + 16 * DIMD + k0, Bsl + 512);
        #pragma unroll
        for (int u = 0; u < 2; u++) {
            int idx = t + u * 256;
            int r = idx >> 2;
            int c8 = (idx & 3) * 8;
            long grow = m0 + r;
            int col = k0 + c8;
            const float* xp = &query[grow * DIMD + col];
            float4 x0 = *(const float4*)xp, x1 = *(const float4*)(xp + 4);
            float mu = mu_q[grow], rs = rs_q[grow];
            float4 g0 = *(const float4*)&qn_g[col], g1 = *(const float4*)&qn_g[col + 4];
            float4 b0 = *(const float4*)&qn_b[col], b1 = *(const float4*)&qn_b[col + 4];
            const float* gp = gamma + bt * DIMD + col;
            const float* bp = beta + bt * DIMD + col;
            float4 gm0 = *(const float4*)gp, gm1 = *(const float4*)(gp + 4);
            float4 be0 = *(const float4*)bp, be1 = *(const float4*)(bp + 4);
            u16 o8[8];
            o8[0] = f2bf(((x0.x - mu) * rs * g0.x + b0.x) * (1.f + gm0.x) + be0.x);
            o8[1] = f2bf(((x0.y - mu) * rs * g0.y + b0.y) * (1.f + gm0.y) + be0.y);
            o8[2] = f2bf(((x0.z - mu) * rs * g0.z + b0.z) * (1.f + gm0.z) + be0.z);
            o8[3] = f2bf(((x0.w - mu) * rs * g0.w + b0.w) * (1.f + gm0.w) + be0.w);
            o8[4] = f2bf(((x1.x - mu) * rs * g1.x + b1.x) * (1.f + gm1.x) + be1.x);
            o8[5] = f2bf(((x1.y - mu) * rs * g1.y + b1.y) * (1.f + gm1.y) + be1.y);
            o8[6] = f2bf(((x1.z - mu) * rs * g1.z + b1.z) * (1.f + gm1.z) + be1.z);
            o8[7] = f2bf(((x1.w - mu) * rs * g1.w + b1.w) * (1.f + gm1.w) + be1.w);
            *(int4*)&As[r * 32 + c8] = *(const int4*)o8;
        }
        __syncthreads();
        bf16x8 af[4], bfr[4];
        #pragma unroll
        for (int i = 0; i < 4; i++) {
            af[i]  = *(const bf16x8*)&As[(mhalf + i * 16 + lm) * 32 + quad * 8];
            bfr[i] = *(const bf16x8*)&Bs[(nhalf + i * 16 + lm) * 32 + quad * 8];
        }
        #pragma unroll
        for (int i = 0; i < 4; i++)
            #pragma unroll
            for (int j = 0; j < 4; j++)
                acc[i][j] = __builtin_amdgcn_mfma_f32_16x16x32_bf16(af[i], bfr[j], acc[i][j], 0, 0, 0);
    }

    float biasj[4];
    #pragma unroll
    for (int j = 0; j < 4; j++) biasj[j] = biasq[n0 + nhalf + j * 16 + lm];

    for (int i = 0; i < 4; i++) {
        __syncthreads();
        #pragma unroll
        for (int j = 0; j < 4; j++)
            #pragma unroll
            for (int r = 0; r < 4; r++)
                smem[((wave >> 1) * 16 + quad * 4 + r) * 128 + nhalf + j * 16 + lm] =
                    f2bf(acc[i][j][r] + biasj[j]);
        __syncthreads();
        #pragma unroll
        for (int u = 0; u < 2; u++) {
            int cch = t + u * 256;
            int R = cch >> 4, ci = cch & 15;
            long grow = m0 + (R >> 4) * 64 + i * 16 + (R & 15);
            int gcol = n0 + ci * 8;
            int4 val = *(const int4*)&smem[R * 128 + ci * 8];
            if (gcol < 512)       *(int4*)(qp + grow * 512 + gcol) = val;
            else if (gcol < 544)  *(int4*)(gq + grow * 32 + (gcol - 512)) = val;
        }
    }
}

// ---------------------------------------------------------------------------
// Flash local attention body (identical logic to round 4/5, LDS carved)
// ---------------------------------------------------------------------------
__device__ __forceinline__ void attn_body(
    int blk, const u16* __restrict__ q_bf, const u16* __restrict__ k_bf,
    const u16* __restrict__ v_bf, const u16* __restrict__ gq_bf,
    const u16* __restrict__ gk_bf, u16* __restrict__ ctx, char* SM)
{
    u16* Ks = (u16*)SM;                       // 16384 B
    u16* Vt = (u16*)(SM + 16384);             // 32768 B
    u16* Pb = (u16*)(SM + 49152);             // 1280 B
    float* part = (float*)(SM + 50432);       // 4096 B  [w*256+q*16+k]
    float* Gb = (float*)(SM + 54528);         // 1024 B  [q*16+k]
    float* alphap = (float*)(SM + 55552);     // 64 B
    float* linv = (float*)(SM + 55616);       // 64 B

    int b = blk >> 6, qs = blk & 63;
    int center = (int)(qs * (255.0f / 63.0f) + 0.5f);
    int lo = center - WIN; if (lo < 0) lo = 0;
    int hi = center + WIN; if (hi > KS - 1) hi = KS - 1;
    int nst = hi - lo + 1;
    long rowq0 = (long)b * NQ + qs * 16;
    long rowk0 = (long)b * NK + lo * 16;

    int t = threadIdx.x;
    int wave = t >> 6, lane = t & 63;
    int lm = lane & 15, quad = lane >> 4;
    int qi = t >> 4, ki = t & 15;

    bf16x8 qf[4];
    #pragma unroll
    for (int f = 0; f < 4; f++)
        qf[f] = *(const bf16x8*)&q_bf[(rowq0 + lm) * DIMD + wave * 128 + f * 32 + quad * 8];
    bf16x8 gqf;
    if (wave == 3) gqf = *(const bf16x8*)&gq_bf[(rowq0 + lm) * RANK + quad * 8];

    int4 kpre[4], vpre[4];
    #pragma unroll
    for (int u = 0; u < 4; u++) {
        int idx = u * 256 + t;
        kpre[u] = *(const int4*)&k_bf[(rowk0 + (idx >> 6)) * DIMD + (idx & 63) * 8];
        int vkv = (idx >> 2) & 15, vdc = (idx & 3) | ((idx >> 6) << 2);
        vpre[u] = *(const int4*)&v_bf[(rowk0 + vkv) * DIMD + vdc * 8];
    }

    float m_run = -1e30f, l_run = 0.f;
    f32x4 acc[8];
    #pragma unroll
    for (int j = 0; j < 8; j++) acc[j] = (f32x4){0.f, 0.f, 0.f, 0.f};

    const float scale = 0.044194173824159216f;   // 512^-0.5
    const float grs = 0.17677669529663687f;      // 32^-0.5

    for (int s = 0; s < nst; s++) {
        int half = s & 1;
        #pragma unroll
        for (int u = 0; u < 4; u++) {
            int idx = u * 256 + t;
            int row = idx >> 6, c = idx & 63;
            *(int4*)&Ks[row * 512 + (c ^ (row & 7)) * 8] = kpre[u];
            int vkv = (idx >> 2) & 15, vdc = (idx & 3) | ((idx >> 6) << 2);
            int kvp = half * 16 + vkv;
            u16 vv[8];
            *(int4*)vv = vpre[u];
            #pragma unroll
            for (int i = 0; i < 8; i++) {
                int d = vdc * 8 + i;
                Vt[d * 32 + (((kvp >> 3) ^ (d & 3)) << 3) + (kvp & 7)] = vv[i];
            }
        }
        __syncthreads();
        if (s + 1 < nst) {
            long rk = rowk0 + (long)(s + 1) * 16;
            #pragma unroll
            for (int u = 0; u < 4; u++) {
                int idx = u * 256 + t;
                kpre[u] = *(const int4*)&k_bf[(rk + (idx >> 6)) * DIMD + (idx & 63) * 8];
                int vkv = (idx >> 2) & 15, vdc = (idx & 3) | ((idx >> 6) << 2);
                vpre[u] = *(const int4*)&v_bf[(rk + vkv) * DIMD + vdc * 8];
            }
        }
        f32x4 sacc = (f32x4){0.f, 0.f, 0.f, 0.f};
        #pragma unroll
        for (int f = 0; f < 4; f++) {
            int cidx = wave * 16 + f * 4 + quad;
            bf16x8 kf = *(const bf16x8*)&Ks[lm * 512 + (cidx ^ (lm & 7)) * 8];
            sacc = __builtin_amdgcn_mfma_f32_16x16x32_bf16(qf[f], kf, sacc, 0, 0, 0);
        }
        #pragma unroll
        for (int r = 0; r < 4; r++) part[wave * 256 + (quad * 4 + r) * 16 + lm] = sacc[r];
        if (wave == 3) {
            bf16x8 gkf = *(const bf16x8*)&gk_bf[(rowk0 + (long)s * 16 + lm) * RANK + quad * 8];
            f32x4 gacc = (f32x4){0.f, 0.f, 0.f, 0.f};
            gacc = __builtin_amdgcn_mfma_f32_16x16x32_bf16(gqf, gkf, gacc, 0, 0, 0);
            #pragma unroll
            for (int r = 0; r < 4; r++) Gb[(quad * 4 + r) * 16 + lm] = gacc[r];
        }
        __syncthreads();
        float sv = (part[qi * 16 + ki] + part[256 + qi * 16 + ki]
                  + part[512 + qi * 16 + ki] + part[768 + qi * 16 + ki]) * scale;
        float gl = Gb[qi * 16 + ki] * grs;
        float sig = 1.f / (1.f + expf(-gl));
        sv += logf(sig + 1e-6f);
        float mx = sv;
        mx = fmaxf(mx, __shfl_xor(mx, 1));
        mx = fmaxf(mx, __shfl_xor(mx, 2));
        mx = fmaxf(mx, __shfl_xor(mx, 4));
        mx = fmaxf(mx, __shfl_xor(mx, 8));
        float m_new = fmaxf(m_run, mx);
        float p = expf(sv - m_new);
        float ps = p;
        ps += __shfl_xor(ps, 1);
        ps += __shfl_xor(ps, 2);
        ps += __shfl_xor(ps, 4);
        ps += __shfl_xor(ps, 8);
        float alpha = expf(m_run - m_new);
        l_run = l_run * alpha + ps;
        m_run = m_new;
        Pb[qi * 40 + half * 16 + ki] = f2bf(p);
        if (half == 1) {
            Pb[qi * 40 + ki] = f2bf(bf2f(Pb[qi * 40 + ki]) * alpha);
        }
        bool dopv = (half == 1) || (s == nst - 1);
        if (dopv && half == 0) Pb[qi * 40 + 16 + ki] = 0;
        if (ki == 0) {
            if (half == 0) alphap[qi] = alpha;
            else           alphap[qi] *= alpha;
            if (s == nst - 1) linv[qi] = 1.f / l_run;
        }
        __syncthreads();
        if (dopv) {
            float ar[4];
            #pragma unroll
            for (int r = 0; r < 4; r++) ar[r] = alphap[quad * 4 + r];
            #pragma unroll
            for (int j = 0; j < 8; j++)
                #pragma unroll
                for (int r = 0; r < 4; r++) acc[j][r] *= ar[r];
            bf16x8 pf = *(const bf16x8*)&Pb[lm * 40 + quad * 8];
            #pragma unroll
            for (int j = 0; j < 8; j++) {
                int d = wave * 128 + j * 16 + lm;
                bf16x8 vf = *(const bf16x8*)&Vt[d * 32 + ((quad ^ (d & 3)) << 3)];
                acc[j] = __builtin_amdgcn_mfma_f32_16x16x32_bf16(pf, vf, acc[j], 0, 0, 0);
            }
            __syncthreads();
        }
    }
    float li[4];
    #pragma unroll
    for (int r = 0; r < 4; r++) li[r] = linv[quad * 4 + r];
    #pragma unroll
    for (int j = 0; j < 8; j++) {
        int d = wave * 128 + j * 16 + lm;
        #pragma unroll
        for (int r = 0; r < 4; r++)
            ctx[(rowq0 + quad * 4 + r) * DIMD + d] = f2bf(acc[j][r] * li[r]);
    }
}

// ===========================================================================
// Mega-kernel: all phases, flag-pipelined. Block ranges (8-aligned starts):
// ===========================================================================
#define B_FILM  0        // 8
#define B_GATE  8        // 128
#define B_TRANS 136      // 1024
#define B_BIAS  1160     // 8
#define B_STAT  1168     // 512
#define B_NORM  1680     // 2048
#define B_KV    3728     // 2304
#define B_QP    6032     // 320
#define B_ATTN  6352     // 512
#define B_OG    6864     // 256
#define B_TOTAL 7120

__global__ __launch_bounds__(256, 2) void mega_kernel(
    int* __restrict__ F,
    const float* __restrict__ query, const float* __restrict__ source,
    const float* __restrict__ ctx0, const float* __restrict__ ctx1,
    const float* __restrict__ qn_g, const float* __restrict__ qn_b,
    const float* __restrict__ kvn_g, const float* __restrict__ kvn_b,
    const float* __restrict__ Wq, const float* __restrict__ bq,
    const float* __restrict__ Wk, const float* __restrict__ bk,
    const float* __restrict__ Wv, const float* __restrict__ bv,
    const float* __restrict__ Wo, const float* __restrict__ bo,
    const float* __restrict__ Wgq, const float* __restrict__ Wgk,
    const float* __restrict__ Wc0, const float* __restrict__ bc0,
    const float* __restrict__ Wc1, const float* __restrict__ bc1,
    const float* __restrict__ Wf, const float* __restrict__ bfv,
    float* __restrict__ gamma, float* __restrict__ beta,
    float* __restrict__ biaskv, float* __restrict__ biasq,
    float* __restrict__ mu_q, float* __restrict__ rs_q,
    u16* __restrict__ sln, u16* __restrict__ kp, u16* __restrict__ vp,
    u16* __restrict__ gk, u16* __restrict__ gq, u16* __restrict__ qp,
    u16* __restrict__ ctxb, u16* __restrict__ Btkv, u16* __restrict__ Btq,
    u16* __restrict__ Bto, float* __restrict__ out)
{
    __shared__ __align__(16) char SM[65536];
    // flag layout
    int* F_SLN = F;          // 256, target 8
    int* F_QST = F + 256;    // 64, target 8
    int* F_FILM = F + 320;   // target 8
    int* F_WKV = F + 321;    // target 581
    int* F_WQ  = F + 322;    // target 323
    int* F_WO  = F + 323;    // target 256
    int* F_KV  = F + 324;    // 256, target 9
    int* F_QP  = F + 580;    // 64, target 5
    int* F_CTX = F + 644;    // 64, target 8

    int bid = blockIdx.x;

    if (bid < B_GATE) {
        film_body(bid, ctx0, ctx1, Wc0, bc0, Wc1, bc1, Wf, bfv, gamma, beta, (float*)SM);
        __syncthreads();
        if (threadIdx.x == 0) sigflag(F_FILM);
    } else if (bid < B_TRANS) {
        int gid = bid - B_GATE;     // 0..127
        if (gid < 64) {
            gatefuse_body(gid, Wk, Wgk, Btkv, 1024, (float*)SM);
            __syncthreads();
            if (threadIdx.x == 0) sigflag(F_WKV);
        } else {
            gatefuse_body(gid - 64, Wq, Wgq, Btq, 512, (float*)SM);
            __syncthreads();
            if (threadIdx.x == 0) sigflag(F_WQ);
        }
    } else if (bid < B_BIAS) {
        int tid = bid - B_TRANS;
        int which = tid >> 8, i = tid & 255;
        float (*tile)[33] = (float(*)[33])SM;
        if (which == 0)      { transpose_body(i, Wk, Btkv, 0, tile);   __syncthreads(); if (threadIdx.x == 0) sigflag(F_WKV); }
        else if (which == 1) { transpose_body(i, Wv, Btkv, 512, tile); __syncthreads(); if (threadIdx.x == 0) sigflag(F_WKV); }
        else if (which == 2) { transpose_body(i, Wq, Btq, 0, tile);    __syncthreads(); if (threadIdx.x == 0) sigflag(F_WQ); }
        else                 { transpose_body(i, Wo, Bto, 0, tile);    __syncthreads(); if (threadIdx.x == 0) sigflag(F_WO); }
    } else if (bid < B_STAT) {
        int cid = bid - B_BIAS;
        if (cid < 5) { biascat3_body(cid, bk, bv, Wgk, biaskv); __syncthreads(); if (threadIdx.x == 0) sigflag(F_WKV); }
        else         { biascat2_body(cid - 5, bq, Wgq, biasq);  __syncthreads(); if (threadIdx.x == 0) sigflag(F_WQ); }
    } else if (bid < B_NORM) {
        int sid = bid - B_STAT;     // 0..511, 16 rows each
        stats_body(sid, query, mu_q, rs_q);
        __syncthreads();
        if (threadIdx.x == 0) sigflag(&F_QST[sid >> 3]);
    } else if (bid < B_KV) {
        int nid = bid - B_NORM;     // 0..2047, 16 rows each
        norm0_body(nid, source, kvn_g, kvn_b, sln);
        __syncthreads();
        if (threadIdx.x == 0) sigflag(&F_SLN[nid >> 3]);
    } else if (bid < B_QP) {
        int l = bid - B_KV;
        int xcd = l & 7, li = l >> 3;
        int by = xcd * 32 + li / 9;
        int bx = li % 9;
        waitflag(F_WKV, 581);
        waitflag(&F_SLN[by], 8);
        gemm_body<3, true>(by * 128, bx * 128, sln, Btkv, biaskv, kp, vp, gk, 1056, (u16*)SM);
        __syncthreads();
        if (threadIdx.x == 0) sigflag(&F_KV[by]);
    } else if (bid < B_ATTN) {
        int l = bid - B_QP;
        int xcd = l & 7, li = l >> 3;
        int by = xcd * 8 + li / 5;
        int bx = li % 5;
        waitflag(F_WQ, 323);
        waitflag(F_FILM, 8);
        waitflag(&F_QST[by], 8);
        qproj_body(by * 128, bx * 128, query, mu_q, rs_q, qn_g, qn_b, gamma, beta,
                   Btq, biasq, qp, gq, (u16*)SM);
        __syncthreads();
        if (threadIdx.x == 0) sigflag(&F_QP[by]);
    } else if (bid < B_OG) {
        int blk = bid - B_ATTN;     // 0..511
        int b = blk >> 6, qs = blk & 63;
        int center = (int)(qs * (255.0f / 63.0f) + 0.5f);
        int lo = center - WIN; if (lo < 0) lo = 0;
        int hi = center + WIN; if (hi > KS - 1) hi = KS - 1;
        int nst = hi - lo + 1;
        int rowk0 = b * NK + lo * 16;
        int gby0 = rowk0 >> 7;
        int gby1 = (rowk0 + nst * 16 - 1) >> 7;
        int qg = (b * NQ + qs * 16) >> 7;
        waitflag(&F_QP[qg], 5);
        waitflag(&F_KV[gby0], 9);
        if (gby1 != gby0) waitflag(&F_KV[gby1], 9);
        attn_body(blk, qp, kp, vp, gq, gk, ctxb, SM);
        __syncthreads();
        if (threadIdx.x == 0) sigflag(&F_CTX[b * 8 + (qs >> 3)]);
    } else {
        int l = bid - B_OG;
        int xcd = l & 7, li = l >> 3;
        int by = xcd * 8 + li / 4;
        int bx = li % 4;
        waitflag(F_WO, 256);
        waitflag(&F_CTX[by], 8);
        gemm_body<1, false>(by * 128, bx * 128, ctxb, Bto, bo, out, nullptr, nullptr,
                            512, (u16*)SM);
    }
}

// ---------------------------------------------------------------------------
extern "C" void kernel_launch(void* const* d_in, const int* in_sizes, int n_in,
                              void* d_out, int out_size, void* d_ws, size_t ws_size,
                              hipStream_t stream) {
    const float* query  = (const float*)d_in[0];
    const float* source = (const float*)d_in[1];
    const float* ctx0   = (const float*)d_in[2];
    const float* ctx1   = (const float*)d_in[3];
    // d_in[4] = mask: structurally known local window, unused
    const float* qn_g  = (const float*)d_in[5];
    const float* qn_b  = (const float*)d_in[6];
    const float* kvn_g = (const float*)d_in[7];
    const float* kvn_b = (const float*)d_in[8];
    const float* Wq = (const float*)d_in[9];   const float* bq = (const float*)d_in[10];
    const float* Wk = (const float*)d_in[11];  const float* bk = (const float*)d_in[12];
    const float* Wv = (const float*)d_in[13];  const float* bv = (const float*)d_in[14];
    const float* Wo = (const float*)d_in[15];  const float* bo = (const float*)d_in[16];
    const float* Wgq = (const float*)d_in[17];
    const float* Wgk = (const float*)d_in[18];
    const float* Wc0 = (const float*)d_in[19]; const float* bc0 = (const float*)d_in[20];
    const float* Wc1 = (const float*)d_in[21]; const float* bc1 = (const float*)d_in[22];
    const float* Wf  = (const float*)d_in[23]; const float* bfv = (const float*)d_in[24];

    // ---- workspace layout: [flags 4 KB][floats][u16 buffers] ----
    int* flags = (int*)d_ws;
    float* fbase  = (float*)((char*)d_ws + 4096);
    float* gamma  = fbase;                      // 4096
    float* beta   = gamma + 4096;               // 4096
    float* biaskv = beta + 4096;                // 1152
    float* biasq  = biaskv + 1152;              // 640
    float* mu_q   = biasq + 640;                // 8192
    float* rs_q   = mu_q + 8192;                // 8192
    u16* u = (u16*)(rs_q + 8192);
    u16* sln  = u;                 u += (long)MK * DIMD;   // LN(source) bf16
    u16* kp   = u;                 u += (long)MK * DIMD;   // k proj bf16
    u16* vp   = u;                 u += (long)MK * DIMD;   // v proj bf16
    u16* gk   = u;                 u += (long)MK * RANK;   // gate_k bf16
    u16* gq   = u;                 u += (long)MQ * RANK;   // gate_q bf16
    u16* qp   = u;                 u += (long)MQ * DIMD;   // q proj bf16
    u16* ctxb = u;                 u += (long)MQ * DIMD;   // attention output bf16
    u16* Btkv = u;                 u += 1152L * DIMD;      // [Wk^T | Wv^T | (Wk·Wgk)^T]
    u16* Btq  = u;                 u += 640L * DIMD;       // [Wq^T | (Wq·Wgq)^T]
    u16* Bto  = u;                 u += 512L * DIMD;       // Wo^T
    float* out = (float*)d_out;

    // zero the flag region (graph-capturable memset node)
    hipMemsetAsync(d_ws, 0, 4096, stream);

    mega_kernel<<<B_TOTAL, 256, 0, stream>>>(
        flags,
        query, source, ctx0, ctx1, qn_g, qn_b, kvn_g, kvn_b,
        Wq, bq, Wk, bk, Wv, bv, Wo, bo, Wgq, Wgk,
        Wc0, bc0, Wc1, bc1, Wf, bfv,
        gamma, beta, biaskv, biasq, mu_q, rs_q,
        sln, kp, vp, gk, gq, qp, ctxb, Btkv, Btq, Bto, out);
}